// Round 1
// baseline (2607.284 us; speedup 1.0000x reference)
//
#include <hip/hip_runtime.h>

// RetinaNet head, bf16 implicit-GEMM conv3x3 via MFMA 16x16x32.
// ws layout (bf16 elements): in_nhwc[13663232] | actA[13663232] | actB[13663232] |
//   weights: cls_t0..3, reg_t0..3 (589824 ea), cls_out (1769472), reg_out (294912)
// total ~95.5 MB.

typedef __bf16 v8bf __attribute__((ext_vector_type(8)));
typedef float f32x4 __attribute__((ext_vector_type(4)));

__device__ __forceinline__ v8bf zero8() {
  v8bf v;
#pragma unroll
  for (int j = 0; j < 8; ++j) v[j] = (__bf16)0.0f;
  return v;
}

struct Lv { int H, W, HW, pb, clsb, regb, l, loc; };

// rowtile id -> level geometry. rowtiles per n: lvl0:100(50 rowpairs x2 wtiles),
// lvl1:25, lvl2:13, lvl3:7, lvl4:4  => 149 total.
__device__ __forceinline__ Lv decode_rt(int rt) {
  Lv v;
  if (rt < 100)      { v.l=0; v.loc=rt;     v.H=100; v.W=100; v.HW=10000; v.pb=0;     v.clsb=0;       v.regb=0;      }
  else if (rt < 125) { v.l=1; v.loc=rt-100; v.H=50;  v.W=50;  v.HW=2500;  v.pb=40000; v.clsb=7200000; v.regb=360000; }
  else if (rt < 138) { v.l=2; v.loc=rt-125; v.H=25;  v.W=25;  v.HW=625;   v.pb=50000; v.clsb=9000000; v.regb=450000; }
  else if (rt < 145) { v.l=3; v.loc=rt-138; v.H=13;  v.W=13;  v.HW=169;   v.pb=52500; v.clsb=9450000; v.regb=472500; }
  else               { v.l=4; v.loc=rt-145; v.H=7;   v.W=7;   v.HW=49;    v.pb=53176; v.clsb=9571680; v.regb=478584; }
  return v;
}

// ---------------- prep: NCHW fp32 -> NHWC bf16 ----------------
__global__ __launch_bounds__(256)
void prep_in(const float* __restrict__ f0, const float* __restrict__ f1,
             const float* __restrict__ f2, const float* __restrict__ f3,
             const float* __restrict__ f4, __bf16* __restrict__ dst)
{
  int oct = blockIdx.x * 256 + threadIdx.x;
  if (oct >= 1707904) return;             // 13663232/8
  int el = oct << 3;
  int c0 = el & 255;
  int pix = el >> 8;
  const float* s; int HW, hw, n;
  if (pix < 40000)      { s = f0; HW = 10000; int p = pix;         n = p / 10000; hw = p - n * 10000; }
  else if (pix < 50000) { s = f1; HW = 2500;  int p = pix - 40000; n = p / 2500;  hw = p - n * 2500;  }
  else if (pix < 52500) { s = f2; HW = 625;   int p = pix - 50000; n = p / 625;   hw = p - n * 625;   }
  else if (pix < 53176) { s = f3; HW = 169;   int p = pix - 52500; n = p / 169;   hw = p - n * 169;   }
  else                  { s = f4; HW = 49;    int p = pix - 53176; n = p / 49;    hw = p - n * 49;    }
  const float* sp = s + (n * 256 + c0) * HW + hw;
  v8bf v;
#pragma unroll
  for (int j = 0; j < 8; ++j) v[j] = (__bf16)sp[j * HW];
  *(v8bf*)(dst + el) = v;
}

// ------------- prep: OIHW fp32 weights -> [cc][tap][co_pad][ci32] bf16 -------------
__global__ __launch_bounds__(256)
void prep_w(const float* __restrict__ src, __bf16* __restrict__ dst, int CO, int COp)
{
  int oct = blockIdx.x * 256 + threadIdx.x;
  int total = 288 * COp;                  // 8*9*COp*4 octets
  if (oct >= total) return;
  int c16 = oct & 3;
  int t2  = oct >> 2;
  int o   = t2 % COp;
  int t3  = t2 / COp;                     // 0..71
  int tap = t3 % 9;
  int cc  = t3 / 9;
  v8bf v = zero8();
  if (o < CO) {
    const float* sp = src + (o * 256 + cc * 32 + c16 * 8) * 9 + tap;
#pragma unroll
    for (int j = 0; j < 8; ++j) v[j] = (__bf16)sp[j * 9];
  }
  *(v8bf*)(dst + (oct << 3)) = v;
}

// ---------------- conv3x3 (implicit GEMM, bf16 MFMA) ----------------
// MODE 0: +bias, ReLU, bf16 NHWC out (CO=256). MODE 1: cls out conv -> fp32 d_out.
// MODE 2: reg out conv -> fp32 d_out.
// Block: 256 thr = 4 waves (2m x 2n), tile 128(M: 2 rows x 64 w) x 128(N).
template<int MODE>
__global__ __launch_bounds__(256)
void conv_k(const __bf16* __restrict__ src, __bf16* __restrict__ dstA,
            float* __restrict__ dstF, const __bf16* __restrict__ wbuf,
            const float* __restrict__ bias, int NT, int COp, int CO)
{
  __shared__ __align__(16) char lds[41472];
  char* ldsA = lds;                        // 4*66*32*2 = 16896 B
  char* ldsB = lds + 16896;                // 3*128*32*2 = 24576 B

  int bid = blockIdx.x;
  int nt = bid % NT;
  int t1 = bid / NT;
  int rt = t1 % 149;
  int n  = t1 / 149;
  Lv L = decode_rt(rt);
  int rp, wt;
  if (L.l == 0) { rp = L.loc >> 1; wt = L.loc & 1; } else { rp = L.loc; wt = 0; }
  int h0 = rp * 2, w0 = wt * 64;
  int aw = L.W - w0; if (aw > 64) aw = 64;

  int tid = threadIdx.x;
  int lane = tid & 63;
  int wv = tid >> 6;
  int wm = wv >> 1, wn = wv & 1;           // wave m-row (0/1), n-half (0/1)
  int la = lane & 15, kg = lane >> 4;

  int rowOK = (h0 + wm) < L.H;
  int fcount = rowOK ? ((aw + 15) >> 4) : 0;   // active 16-wide m-frags (<=4)

  f32x4 acc[4][4];
#pragma unroll
  for (int f = 0; f < 4; ++f)
#pragma unroll
    for (int j = 0; j < 4; ++j)
#pragma unroll
      for (int k = 0; k < 4; ++k) acc[f][j][k] = 0.0f;

  const __bf16* srcn = src + (L.pb + n * L.HW) * 256;
  const __bf16* wnt  = wbuf + nt * 4096;   // + ((cc*9+tap)*COp + co)*32

  for (int cc = 0; cc < 8; ++cc) {
    __syncthreads();                       // prev reads of A and B done
    // stage A: rows h0-1..h0+2, cols w0-1..w0+64, 32 ci
    for (int q = tid; q < 1056; q += 256) {
      int c16 = q & 3; int colr = q >> 2;
      int col = colr % 66; int r = colr / 66;
      int row = h0 - 1 + r; int wc = w0 - 1 + col;
      v8bf v = zero8();
      if ((unsigned)row < (unsigned)L.H && (unsigned)wc < (unsigned)L.W)
        v = *(const v8bf*)(srcn + ((row * L.W + wc) << 8) + cc * 32 + c16 * 8);
      int byte = (((r * 66 + col) << 6) + (c16 << 4)) ^ ((col & 7) << 4);
      *(v8bf*)(ldsA + byte) = v;
    }
#pragma unroll
    for (int tg = 0; tg < 3; ++tg) {
      if (tg) __syncthreads();             // prev tap-group B reads done
      // stage B: 3 taps x 128 co x 32 ci
      for (int q = tid; q < 1536; q += 256) {
        int c16 = q & 3; int co = (q >> 2) & 127; int tt = q >> 9;
        int tap = tg * 3 + tt;
        v8bf v = *(const v8bf*)(wnt + (((cc * 9 + tap) * COp + co) << 5) + (c16 << 3));
        int byte = (((tt * 128 + co) << 6) + (c16 << 4)) ^ ((co & 7) << 4);
        *(v8bf*)(ldsB + byte) = v;
      }
      __syncthreads();                     // staged A+B visible
      if (fcount) {
#pragma unroll
        for (int tt2 = 0; tt2 < 3; ++tt2) {
          int tap = tg * 3 + tt2;
          int dh = tap / 3 - 1, dw = tap % 3 - 1;
          int colb = la + dw + 1;
          int abase = (((wm + dh + 1) * 66 + colb) << 6) + (kg << 4);
          int axor = (colb & 7) << 4;
          int bbase = ((wn * 64 + la) << 6) + (kg << 4) + tt2 * 8192;
          int bxor = (la & 7) << 4;
          v8bf bfr[4];
#pragma unroll
          for (int nj = 0; nj < 4; ++nj)
            bfr[nj] = *(const v8bf*)(ldsB + ((bbase + nj * 1024) ^ bxor));
          v8bf afr[4];
#pragma unroll
          for (int f = 0; f < 4; ++f)
            if (f < fcount)
              afr[f] = *(const v8bf*)(ldsA + ((abase + f * 1024) ^ axor));
#pragma unroll
          for (int f = 0; f < 4; ++f)
            if (f < fcount)
#pragma unroll
              for (int nj = 0; nj < 4; ++nj)
                acc[f][nj] = __builtin_amdgcn_mfma_f32_16x16x32_bf16(afr[f], bfr[nj], acc[f][nj], 0, 0, 0);
        }
      }
    }
  }

  if (!fcount) return;
  int hrow = h0 + wm;
  int pixrow = L.pb + n * L.HW + hrow * L.W;
#pragma unroll
  for (int f = 0; f < 4; ++f) {
    if (f < fcount) {
#pragma unroll
      for (int nj = 0; nj < 4; ++nj) {
        int cob = nt * 128 + wn * 64 + nj * 16 + la;
        float bs = (cob < CO) ? bias[cob] : 0.0f;
#pragma unroll
        for (int r = 0; r < 4; ++r) {
          int wq = f * 16 + kg * 4 + r;    // D row = kg*4 + r
          if (wq < aw) {
            float vv = acc[f][nj][r] + bs;
            if (MODE == 0) {
              vv = fmaxf(vv, 0.0f);
              dstA[((pixrow + w0 + wq) << 8) + cob] = (__bf16)vv;
            } else if (MODE == 1) {
              if (cob < 720)
                dstF[n * 9606960 + L.clsb + (hrow * L.W + w0 + wq) * 720 + cob] = vv;
            } else {
              if (cob < 36)
                dstF[38427840 + n * 480348 + L.regb + (hrow * L.W + w0 + wq) * 36 + cob] = vv;
            }
          }
        }
      }
    }
  }
}

extern "C" void kernel_launch(void* const* d_in, const int* in_sizes, int n_in,
                              void* d_out, int out_size, void* d_ws, size_t ws_size,
                              hipStream_t stream) {
  (void)in_sizes; (void)n_in; (void)out_size; (void)ws_size;
  const float* feat0 = (const float*)d_in[0];
  const float* feat1 = (const float*)d_in[1];
  const float* feat2 = (const float*)d_in[2];
  const float* feat3 = (const float*)d_in[3];
  const float* feat4 = (const float*)d_in[4];
  const float* cls_w  = (const float*)d_in[5];
  const float* cls_b  = (const float*)d_in[6];
  const float* cls_ow = (const float*)d_in[7];
  const float* cls_ob = (const float*)d_in[8];
  const float* reg_w  = (const float*)d_in[9];
  const float* reg_b  = (const float*)d_in[10];
  const float* reg_ow = (const float*)d_in[11];
  const float* reg_ob = (const float*)d_in[12];
  float* out = (float*)d_out;

  const int ACT = 13663232;                // bf16 elements per activation buffer
  const int WT  = 589824;                  // per 256->256 conv weight tensor
  __bf16* base    = (__bf16*)d_ws;
  __bf16* in_nhwc = base;
  __bf16* actA    = base + ACT;
  __bf16* actB    = base + 2 * ACT;
  __bf16* wb      = base + 3 * ACT;
  __bf16* wb_cls[4], *wb_reg[4];
  for (int li = 0; li < 4; ++li) { wb_cls[li] = wb + li * WT; wb_reg[li] = wb + (4 + li) * WT; }
  __bf16* wb_co = wb + 8 * WT;             // 8*9*768*32 = 1769472
  __bf16* wb_ro = wb_co + 1769472;         // 8*9*128*32 = 294912

  prep_in<<<6672, 256, 0, stream>>>(feat0, feat1, feat2, feat3, feat4, in_nhwc);
  for (int li = 0; li < 4; ++li) {
    prep_w<<<288, 256, 0, stream>>>(cls_w + li * WT, wb_cls[li], 256, 256);
    prep_w<<<288, 256, 0, stream>>>(reg_w + li * WT, wb_reg[li], 256, 256);
  }
  prep_w<<<864, 256, 0, stream>>>(cls_ow, wb_co, 720, 768);
  prep_w<<<144, 256, 0, stream>>>(reg_ow, wb_ro, 36, 128);

  const int GT = 149 * 4 * 2;              // tower grid: 1192
  // cls branch
  conv_k<0><<<GT, 256, 0, stream>>>(in_nhwc, actA, nullptr, wb_cls[0], cls_b + 0,   2, 256, 256);
  conv_k<0><<<GT, 256, 0, stream>>>(actA,    actB, nullptr, wb_cls[1], cls_b + 256, 2, 256, 256);
  conv_k<0><<<GT, 256, 0, stream>>>(actB,    actA, nullptr, wb_cls[2], cls_b + 512, 2, 256, 256);
  conv_k<0><<<GT, 256, 0, stream>>>(actA,    actB, nullptr, wb_cls[3], cls_b + 768, 2, 256, 256);
  conv_k<1><<<149 * 4 * 6, 256, 0, stream>>>(actB, nullptr, out, wb_co, cls_ob, 6, 768, 720);
  // reg branch
  conv_k<0><<<GT, 256, 0, stream>>>(in_nhwc, actA, nullptr, wb_reg[0], reg_b + 0,   2, 256, 256);
  conv_k<0><<<GT, 256, 0, stream>>>(actA,    actB, nullptr, wb_reg[1], reg_b + 256, 2, 256, 256);
  conv_k<0><<<GT, 256, 0, stream>>>(actB,    actA, nullptr, wb_reg[2], reg_b + 512, 2, 256, 256);
  conv_k<0><<<GT, 256, 0, stream>>>(actA,    actB, nullptr, wb_reg[3], reg_b + 768, 2, 256, 256);
  conv_k<2><<<149 * 4 * 1, 256, 0, stream>>>(actB, nullptr, out, wb_ro, reg_ob, 1, 128, 36);
}

// Round 2
// 1160.039 us; speedup vs baseline: 2.2476x; 2.2476x over previous
//
#include <hip/hip_runtime.h>

// RetinaNet head, bf16 implicit-GEMM conv3x3 via MFMA 16x16x32.
// Round 2: flat-pixel M tiles (128 px), global_load_lds staging, 1-barrier
// tap phases with double-buffered B, involutive XOR LDS swizzle.
//
// ws layout (bf16 elems): in_nhwc[13663232] | actA[13663232] | actB[13663232] |
//   wb_cls[4]x589824 | wb_reg[4]x589824 | wb_co 1769472 | wb_ro 294912 | zp 4096
// B pack layout: [nt][cc 8][tap 9][co 128][ci32 as 4x16B pieces, piece XOR-swizzled]

typedef __bf16 v8bf __attribute__((ext_vector_type(8)));
typedef float f32x4 __attribute__((ext_vector_type(4)));

__device__ __forceinline__ v8bf zero8() {
  v8bf v;
#pragma unroll
  for (int j = 0; j < 8; ++j) v[j] = (__bf16)0.0f;
  return v;
}

__device__ __forceinline__ void glds16(const void* g, void* l) {
  __builtin_amdgcn_global_load_lds((const __attribute__((address_space(1))) unsigned int*)g,
                                   (__attribute__((address_space(3))) unsigned int*)l, 16, 0, 0);
}

// ---------------- prep: NCHW fp32 -> NHWC bf16 ----------------
__global__ __launch_bounds__(256)
void prep_in(const float* __restrict__ f0, const float* __restrict__ f1,
             const float* __restrict__ f2, const float* __restrict__ f3,
             const float* __restrict__ f4, __bf16* __restrict__ dst)
{
  int oct = blockIdx.x * 256 + threadIdx.x;
  if (oct >= 1707904) return;             // 13663232/8
  int el = oct << 3;
  int c0 = el & 255;
  int pix = el >> 8;
  const float* s; int HW, hw, n;
  if (pix < 40000)      { s = f0; HW = 10000; int p = pix;         n = p / 10000; hw = p - n * 10000; }
  else if (pix < 50000) { s = f1; HW = 2500;  int p = pix - 40000; n = p / 2500;  hw = p - n * 2500;  }
  else if (pix < 52500) { s = f2; HW = 625;   int p = pix - 50000; n = p / 625;   hw = p - n * 625;   }
  else if (pix < 53176) { s = f3; HW = 169;   int p = pix - 52500; n = p / 169;   hw = p - n * 169;   }
  else                  { s = f4; HW = 49;    int p = pix - 53176; n = p / 49;    hw = p - n * 49;    }
  const float* sp = s + (n * 256 + c0) * HW + hw;
  v8bf v;
#pragma unroll
  for (int j = 0; j < 8; ++j) v[j] = (__bf16)sp[j * HW];
  *(v8bf*)(dst + el) = v;
}

// ------ prep: OIHW fp32 -> packed B [nt][cc][tap][co][piece^swz] bf16 ------
__global__ __launch_bounds__(256)
void prep_w(const float* __restrict__ src, __bf16* __restrict__ dst, int NTp, int CO)
{
  int t = blockIdx.x * 256 + threadIdx.x;
  int total = NTp * 8 * 9 * 128 * 4;
  if (t >= total) return;
  int p = t & 3;
  int x = t >> 2;
  int co = x & 127; x >>= 7;
  int tap = x % 9; x /= 9;
  int cc = x & 7; int nt = x >> 3;
  int l = p ^ ((co >> 1) & 3);            // logical piece held at physical p
  int cog = nt * 128 + co;
  v8bf v = zero8();
  if (cog < CO) {
    const float* sp = src + ((size_t)cog * 256 + cc * 32 + l * 8) * 9 + tap;
#pragma unroll
    for (int j = 0; j < 8; ++j) v[j] = (__bf16)sp[j * 9];
  }
  *(v8bf*)(dst + ((size_t)(((nt * 8 + cc) * 9 + tap) * 128 + co) * 32 + p * 8)) = v;
}

// ---------------- conv3x3 (implicit GEMM, bf16 MFMA) ----------------
// MODE 0: +bias, ReLU, bf16 NHWC out. MODE 1: cls out -> fp32 d_out. MODE 2: reg out.
// 256 thr = 4 waves (2m x 2n). Tile: 128 flat pixels x 128 co.
template<int MODE>
__global__ __launch_bounds__(256, 3)
void conv_k(const __bf16* __restrict__ src, __bf16* __restrict__ dstA,
            float* __restrict__ dstF, const __bf16* __restrict__ wbuf,
            const float* __restrict__ bias, const __bf16* __restrict__ zpg,
            int NT, int CO)
{
  __shared__ __align__(16) char lds[49152];
  char* ldsA = lds;                        // 512 pos * 64B
  char* ldsB = lds + 32768;                // 2 * 8192

  int bid = blockIdx.x;
  int nt = bid % NT, mt = bid / NT;
  int n = mt / 107, r = mt - n * 107;
  int W, H, HW, pbase, ob, t;
  if (MODE == 1) {
    if (r < 79)       { W=100;H=100;HW=10000;pbase=0;     ob=0;       t=r; }
    else if (r < 99)  { W=50; H=50; HW=2500; pbase=40000; ob=7200000; t=r-79; }
    else if (r < 104) { W=25; H=25; HW=625;  pbase=50000; ob=9000000; t=r-99; }
    else if (r < 106) { W=13; H=13; HW=169;  pbase=52500; ob=9450000; t=r-104; }
    else              { W=7;  H=7;  HW=49;   pbase=53176; ob=9571680; t=r-106; }
  } else {
    if (r < 79)       { W=100;H=100;HW=10000;pbase=0;     ob=0;      t=r; }
    else if (r < 99)  { W=50; H=50; HW=2500; pbase=40000; ob=360000; t=r-79; }
    else if (r < 104) { W=25; H=25; HW=625;  pbase=50000; ob=450000; t=r-99; }
    else if (r < 106) { W=13; H=13; HW=169;  pbase=52500; ob=472500; t=r-104; }
    else              { W=7;  H=7;  HW=49;   pbase=53176; ob=478584; t=r-106; }
  }
  int p0 = t << 7;
  int npx = HW - p0; if (npx > 128) npx = 128;
  int pend = p0 + npx - 1;
  int Wp = W + 2;
  int rowlo = p0 / W - 1;

  int tid = threadIdx.x, lane = tid & 63, wv = tid >> 6;
  int wm = wv >> 1, wn = wv & 1, la = lane & 15, kg = lane >> 4;
  int i0 = wv * 8;

  // per-lane A source addresses (one per wave-load), advance +64B per cc
  const char* addrA[8];
#pragma unroll
  for (int j = 0; j < 8; ++j) {
    int i = i0 + j;
    int pos = i * 16 + (lane >> 2);
    int h = pos / Wp;
    int wc = pos - h * Wp - 1;
    int ar = rowlo + h;
    int pl = (lane & 3) ^ ((pos >> 1) & 3);   // pre-swizzled source piece
    bool ok = (ar >= 0) & (ar < H) & (wc >= 0) & (wc < W);
    addrA[j] = ok ? (const char*)(src + (((size_t)(pbase + n * HW + ar * W + wc)) << 8) + pl * 8)
                  : (const char*)zpg + (lane & 3) * 16;
  }

  // per-lane read base positions (pixel -> staged pos), per m-frag
  int pos0[4];
  int fvalid[4];
#pragma unroll
  for (int f = 0; f < 4; ++f) {
    int fg = wm * 4 + f;
    fvalid[f] = (fg * 16 < npx);
    int p = p0 + fg * 16 + la; if (p > pend) p = pend;
    int h = p / W, w = p - h * W;
    pos0[f] = (h - rowlo) * Wp + (w + 1);
  }

  const char* bsrc = (const char*)wbuf + (size_t)nt * 589824 + wv * 2048 + lane * 16;

  f32x4 acc[4][4];
#pragma unroll
  for (int f = 0; f < 4; ++f)
#pragma unroll
    for (int j = 0; j < 4; ++j)
#pragma unroll
      for (int k = 0; k < 4; ++k) acc[f][j][k] = 0.0f;

#define ISSUE_A() do { _Pragma("unroll") \
    for (int j = 0; j < 8; ++j) { glds16(addrA[j], ldsA + (i0 + j) * 1024); addrA[j] += 64; } } while (0)
#define ISSUE_B(q, buf) do { const char* s_ = bsrc + (q) * 8192; \
    char* d_ = ldsB + (buf) * 8192 + wv * 2048; \
    glds16(s_, d_); glds16(s_ + 1024, d_ + 1024); } while (0)

  ISSUE_A();
  ISSUE_B(0, 0);
  int pb = 0;

  for (int cc = 0; cc < 8; ++cc) {
#pragma unroll
    for (int tap = 0; tap < 9; ++tap) {
      __syncthreads();                      // drains this wave's issued loads
      int q = cc * 9 + tap;
      if (q < 71) ISSUE_B(q + 1, pb ^ 1);
      const int dh = tap / 3 - 1, dw = tap % 3 - 1;
      int dt = dh * Wp + dw;
      v8bf bfr[4];
#pragma unroll
      for (int nj = 0; nj < 4; ++nj) {
        int co = wn * 64 + nj * 16 + la;
        int bb = ((co << 6) + (kg << 4)) ^ (((co >> 1) & 3) << 4);
        bfr[nj] = *(const v8bf*)(ldsB + pb * 8192 + bb);
      }
#pragma unroll
      for (int f = 0; f < 4; ++f) {
        if (fvalid[f]) {
          int pos = pos0[f] + dt;
          int ab = ((pos << 6) + (kg << 4)) ^ (((pos >> 1) & 3) << 4);
          v8bf af = *(const v8bf*)(ldsA + ab);
#pragma unroll
          for (int nj = 0; nj < 4; ++nj)
            acc[f][nj] = __builtin_amdgcn_mfma_f32_16x16x32_bf16(af, bfr[nj], acc[f][nj], 0, 0, 0);
        }
      }
      pb ^= 1;
      if (tap == 8 && cc < 7) { __syncthreads(); ISSUE_A(); }
    }
  }

  // epilogue
#pragma unroll
  for (int f = 0; f < 4; ++f) {
    int fg = wm * 4 + f;
    if (fg * 16 < npx) {
#pragma unroll
      for (int nj = 0; nj < 4; ++nj) {
        int cob = nt * 128 + wn * 64 + nj * 16 + la;
        float bs = (cob < CO) ? bias[cob] : 0.0f;
#pragma unroll
        for (int rr = 0; rr < 4; ++rr) {
          int pl = fg * 16 + kg * 4 + rr;
          if (pl < npx) {
            float vv = acc[f][nj][rr] + bs;
            int pix = p0 + pl;
            if (MODE == 0) {
              vv = fmaxf(vv, 0.0f);
              dstA[(((size_t)(pbase + n * HW + pix)) << 8) + cob] = (__bf16)vv;
            } else if (MODE == 1) {
              if (cob < 720)
                dstF[(size_t)n * 9606960 + ob + (size_t)pix * 720 + cob] = vv;
            } else {
              if (cob < 36)
                dstF[38427840 + (size_t)n * 480348 + ob + (size_t)pix * 36 + cob] = vv;
            }
          }
        }
      }
    }
  }
#undef ISSUE_A
#undef ISSUE_B
}

extern "C" void kernel_launch(void* const* d_in, const int* in_sizes, int n_in,
                              void* d_out, int out_size, void* d_ws, size_t ws_size,
                              hipStream_t stream) {
  (void)in_sizes; (void)n_in; (void)out_size; (void)ws_size;
  const float* feat0 = (const float*)d_in[0];
  const float* feat1 = (const float*)d_in[1];
  const float* feat2 = (const float*)d_in[2];
  const float* feat3 = (const float*)d_in[3];
  const float* feat4 = (const float*)d_in[4];
  const float* cls_w  = (const float*)d_in[5];
  const float* cls_b  = (const float*)d_in[6];
  const float* cls_ow = (const float*)d_in[7];
  const float* cls_ob = (const float*)d_in[8];
  const float* reg_w  = (const float*)d_in[9];
  const float* reg_b  = (const float*)d_in[10];
  const float* reg_ow = (const float*)d_in[11];
  const float* reg_ob = (const float*)d_in[12];
  float* out = (float*)d_out;

  const int ACT = 13663232;                // bf16 elements per activation buffer
  const int WT  = 589824;                  // per 256->256 conv weight tensor (packed)
  __bf16* base    = (__bf16*)d_ws;
  __bf16* in_nhwc = base;
  __bf16* actA    = base + ACT;
  __bf16* actB    = base + 2 * ACT;
  __bf16* wb      = base + 3 * ACT;
  __bf16* wb_cls[4], *wb_reg[4];
  for (int li = 0; li < 4; ++li) { wb_cls[li] = wb + li * WT; wb_reg[li] = wb + (4 + li) * WT; }
  __bf16* wb_co = wb + 8 * WT;             // 6*8*9*128*32 = 1769472
  __bf16* wb_ro = wb_co + 1769472;         // 1*8*9*128*32 = 294912
  __bf16* zpg   = wb_ro + 294912;          // 4096 elems = 8KB zero page

  hipMemsetAsync(zpg, 0, 8192, stream);
  prep_in<<<6672, 256, 0, stream>>>(feat0, feat1, feat2, feat3, feat4, in_nhwc);
  for (int li = 0; li < 4; ++li) {
    prep_w<<<288, 256, 0, stream>>>(cls_w + li * WT, wb_cls[li], 2, 256);
    prep_w<<<288, 256, 0, stream>>>(reg_w + li * WT, wb_reg[li], 2, 256);
  }
  prep_w<<<864, 256, 0, stream>>>(cls_ow, wb_co, 6, 720);
  prep_w<<<144, 256, 0, stream>>>(reg_ow, wb_ro, 1, 36);

  const int GT = 428 * 2;                  // tower grid: 856
  // cls branch
  conv_k<0><<<GT, 256, 0, stream>>>(in_nhwc, actA, nullptr, wb_cls[0], cls_b + 0,   zpg, 2, 256);
  conv_k<0><<<GT, 256, 0, stream>>>(actA,    actB, nullptr, wb_cls[1], cls_b + 256, zpg, 2, 256);
  conv_k<0><<<GT, 256, 0, stream>>>(actB,    actA, nullptr, wb_cls[2], cls_b + 512, zpg, 2, 256);
  conv_k<0><<<GT, 256, 0, stream>>>(actA,    actB, nullptr, wb_cls[3], cls_b + 768, zpg, 2, 256);
  conv_k<1><<<428 * 6, 256, 0, stream>>>(actB, nullptr, out, wb_co, cls_ob, zpg, 6, 720);
  // reg branch
  conv_k<0><<<GT, 256, 0, stream>>>(in_nhwc, actA, nullptr, wb_reg[0], reg_b + 0,   zpg, 2, 256);
  conv_k<0><<<GT, 256, 0, stream>>>(actA,    actB, nullptr, wb_reg[1], reg_b + 256, zpg, 2, 256);
  conv_k<0><<<GT, 256, 0, stream>>>(actB,    actA, nullptr, wb_reg[2], reg_b + 512, zpg, 2, 256);
  conv_k<0><<<GT, 256, 0, stream>>>(actA,    actB, nullptr, wb_reg[3], reg_b + 768, zpg, 2, 256);
  conv_k<2><<<428, 256, 0, stream>>>(actB, nullptr, out, wb_ro, reg_ob, zpg, 1, 36);
}